// Round 2
// baseline (821.025 us; speedup 1.0000x reference)
//
#include <hip/hip_runtime.h>
#include <math.h>

// ---- problem constants ----
#define TOKS   65536      // B*D*H*W = 2*8*64*64
#define DIMC   192
#define NWIN   512        // windows total (Bw)
#define NLOC   256        // windows per batch (nW)
#define NTOK   128        // tokens per window
#define NHEAD  6
#define HDIM   32
#define MLPH   384

static __device__ __forceinline__ float gelu_exact(float v) {
    return 0.5f * v * (1.f + erff(v * 0.70710678118654752f));
}

// workspace layout (float offsets)
#define OFF_XW   0u            // 65536*192 = 12582912  (xw / attn_out / y)
#define OFF_Q    12582912u     // q  (w,h,n,d)
#define OFF_K    25165824u     // k  ; h (fc1 out) overlays k..v
#define OFF_V    37748736u     // v
#define OFF_BF   50331648u     // bias_full[6][128][128] = 98304
// total = 50429952 floats = ~202 MB

// ---------------- rel-pos bias gather: bias_full[h][n][m] ----------------
__global__ __launch_bounds__(256) void k_bias(const float* __restrict__ rpb,
                                              const int* __restrict__ rpi,
                                              float* __restrict__ biasf) {
    int idx = blockIdx.x * 256 + threadIdx.x;   // 6*16384 = 98304 exact
    int h = idx >> 14;
    int nm = idx & 16383;
    biasf[idx] = rpb[rpi[nm] * 6 + h];
}

// ---------------- LayerNorm (optionally fused roll+window-partition gather) ----------------
// PERMUTE: out token tk is window-ordered; source is x[(p+shift) mod dims]
template<bool PERMUTE>
__global__ __launch_bounds__(256) void k_ln(const float* __restrict__ x,
                                            const float* __restrict__ gamma,
                                            const float* __restrict__ beta,
                                            float* __restrict__ out) {
    int tid  = threadIdx.x;
    int lane = tid & 63, wv = tid >> 6;
    int tk = blockIdx.x * 4 + wv;               // output token index
    size_t src;
    if (PERMUTE) {
        int w_all = tk >> 7, t = tk & 127;
        int b  = w_all >> 8, rem = w_all & 255;
        int di = rem >> 6, hi = (rem >> 3) & 7, wi = rem & 7;
        int qd = (di * 2 + (t >> 6) + 1) & 7;
        int qh = (hi * 8 + ((t >> 3) & 7) + 4) & 63;
        int qw = (wi * 8 + (t & 7) + 4) & 63;
        src = ((size_t)(((b * 8 + qd) * 64 + qh) * 64 + qw)) * DIMC;
    } else {
        src = (size_t)tk * DIMC;
    }
    float v0 = x[src + lane];
    float v1 = x[src + 64 + lane];
    float v2 = x[src + 128 + lane];
    float s  = v0 + v1 + v2;
    float sq = v0 * v0 + v1 * v1 + v2 * v2;
    #pragma unroll
    for (int off = 32; off; off >>= 1) {
        s  += __shfl_xor(s, off);
        sq += __shfl_xor(sq, off);
    }
    float mu   = s * (1.f / 192.f);
    float var  = sq * (1.f / 192.f) - mu * mu;
    float rstd = rsqrtf(var + 1e-5f);
    size_t o = (size_t)tk * DIMC;
    out[o + lane]       = (v0 - mu) * rstd * gamma[lane]       + beta[lane];
    out[o + 64 + lane]  = (v1 - mu) * rstd * gamma[64 + lane]  + beta[64 + lane];
    out[o + 128 + lane] = (v2 - mu) * rstd * gamma[128 + lane] + beta[128 + lane];
}

// ---------------- tiled SGEMM: C[m,n] = dot(A[m,:], B[n,:]) + bias[n], fused epilogues ----------------
// A: [M,K] row-major, B: [N,K] row-major (weight (out,in)). BM=128 BN=64 BK=32, 256 thr, 8x4/thr.
// MODE 0: QKV scatter (q scaled) -> out + sel*12582912, layout (w,head,n,d)
// MODE 1: proj -> scatter via roll-reverse mapping, += aux(x), write out (=xres)
// MODE 2: fc1 -> gelu -> out[m*N+n]
// MODE 3: fc2 -> + aux[m*192+n] -> out[m*192+n]
template<int MODE>
__global__ __launch_bounds__(256) void k_gemm(const float* __restrict__ A,
                                              const float* __restrict__ B,
                                              const float* __restrict__ bias,
                                              float* __restrict__ out,
                                              const float* __restrict__ aux,
                                              int M, int N, int K) {
    __shared__ float As[32][132];   // [k][m], padded rows, inner read = broadcast-friendly
    __shared__ float Bs[32][68];    // [k][n]
    int tid = threadIdx.x;
    int tx = tid & 15, ty = tid >> 4;
    int m0 = blockIdx.x * 128, n0 = blockIdx.y * 64;
    const float* Ab = A + (size_t)m0 * K;
    const float* Bb = B + (size_t)n0 * K;
    float acc[8][4] = {};
    for (int k0 = 0; k0 < K; k0 += 32) {
        #pragma unroll
        for (int j = 0; j < 4; ++j) {           // A: 128x32 = 1024 float4
            int id = j * 256 + tid;
            int r = id >> 3, c = (id & 7) << 2;
            float4 a = *(const float4*)&Ab[(size_t)r * K + k0 + c];
            As[c + 0][r] = a.x; As[c + 1][r] = a.y;
            As[c + 2][r] = a.z; As[c + 3][r] = a.w;
        }
        #pragma unroll
        for (int j = 0; j < 2; ++j) {           // B: 64x32 = 512 float4
            int id = j * 256 + tid;
            int r = id >> 3, c = (id & 7) << 2;
            float4 b = *(const float4*)&Bb[(size_t)r * K + k0 + c];
            Bs[c + 0][r] = b.x; Bs[c + 1][r] = b.y;
            Bs[c + 2][r] = b.z; Bs[c + 3][r] = b.w;
        }
        __syncthreads();
        #pragma unroll
        for (int kk = 0; kk < 32; ++kk) {
            float4 b4 = *(float4*)&Bs[kk][tx * 4];
            float4 a0 = *(float4*)&As[kk][ty * 8];
            float4 a1 = *(float4*)&As[kk][ty * 8 + 4];
            float a[8] = {a0.x, a0.y, a0.z, a0.w, a1.x, a1.y, a1.z, a1.w};
            float b[4] = {b4.x, b4.y, b4.z, b4.w};
            #pragma unroll
            for (int i = 0; i < 8; ++i)
                #pragma unroll
                for (int j = 0; j < 4; ++j)
                    acc[i][j] += a[i] * b[j];
        }
        __syncthreads();
    }
    int mrow = m0 + ty * 8;
    int ncol = n0 + tx * 4;
    float bb0 = bias[ncol], bb1 = bias[ncol + 1], bb2 = bias[ncol + 2], bb3 = bias[ncol + 3];

    if (MODE == 0) {
        int sel = ncol / 192, rem = ncol - sel * 192;
        int head = rem >> 5, dd = rem & 31;
        float scale = (sel == 0) ? 0.17677669529663687f : 1.f;
        float* dst0 = out + (size_t)sel * 12582912u;
        #pragma unroll
        for (int i = 0; i < 8; ++i) {
            int m = mrow + i, w = m >> 7, t = m & 127;
            float4 v;
            v.x = (acc[i][0] + bb0) * scale; v.y = (acc[i][1] + bb1) * scale;
            v.z = (acc[i][2] + bb2) * scale; v.w = (acc[i][3] + bb3) * scale;
            *(float4*)&dst0[((size_t)((w * 6 + head) * 128 + t)) * 32 + dd] = v;
        }
    } else if (MODE == 1) {
        #pragma unroll
        for (int i = 0; i < 8; ++i) {
            int m = mrow + i, w_all = m >> 7, t = m & 127;
            int b  = w_all >> 8, rem = w_all & 255;
            int di = rem >> 6, hi = (rem >> 3) & 7, wi = rem & 7;
            int qd = (di * 2 + (t >> 6) + 1) & 7;
            int qh = (hi * 8 + ((t >> 3) & 7) + 4) & 63;
            int qw = (wi * 8 + (t & 7) + 4) & 63;
            size_t dtok = (size_t)(((b * 8 + qd) * 64 + qh) * 64 + qw);
            float4 xr = *(const float4*)&aux[dtok * DIMC + ncol];
            float4 v;
            v.x = acc[i][0] + bb0 + xr.x; v.y = acc[i][1] + bb1 + xr.y;
            v.z = acc[i][2] + bb2 + xr.z; v.w = acc[i][3] + bb3 + xr.w;
            *(float4*)&out[dtok * DIMC + ncol] = v;
        }
    } else if (MODE == 2) {
        #pragma unroll
        for (int i = 0; i < 8; ++i) {
            int m = mrow + i;
            float4 v;
            v.x = gelu_exact(acc[i][0] + bb0); v.y = gelu_exact(acc[i][1] + bb1);
            v.z = gelu_exact(acc[i][2] + bb2); v.w = gelu_exact(acc[i][3] + bb3);
            *(float4*)&out[(size_t)m * N + ncol] = v;
        }
    } else {
        #pragma unroll
        for (int i = 0; i < 8; ++i) {
            int m = mrow + i;
            float4 xr = *(const float4*)&aux[(size_t)m * DIMC + ncol];
            float4 v;
            v.x = acc[i][0] + bb0 + xr.x; v.y = acc[i][1] + bb1 + xr.y;
            v.z = acc[i][2] + bb2 + xr.z; v.w = acc[i][3] + bb3 + xr.w;
            *(float4*)&out[(size_t)m * DIMC + ncol] = v;
        }
    }
}

// ---------------- attention: one block per (window, head) ----------------
// 256 thr: thread = (row r = tid>>1, half hf = tid&1) handles 64 score cols, softmax in-register.
__global__ __launch_bounds__(256) void k_attn(const float* __restrict__ qb,
                                              const float* __restrict__ kb,
                                              const float* __restrict__ vb,
                                              const float* __restrict__ biasf,
                                              const float* __restrict__ mask,
                                              float* __restrict__ attn_out) {
    __shared__ float Ks[128][32];
    __shared__ float Vs[128][32];
    int wh = blockIdx.x;                 // 0..3071
    int w_all = wh / 6, head = wh - w_all * 6;
    int wl = w_all & 255;
    int tid = threadIdx.x;
    size_t base = (size_t)(w_all * 6 + head) * (128 * 32);
    const float* kg = kb + base;
    const float* vg = vb + base;
    #pragma unroll
    for (int j = 0; j < 4; ++j) {        // 1024 float4 each, linear -> conflict-free
        int id = j * 256 + tid;
        int r = id >> 3, c = (id & 7) << 2;
        *(float4*)&Ks[r][c] = *(const float4*)&kg[r * 32 + c];
        *(float4*)&Vs[r][c] = *(const float4*)&vg[r * 32 + c];
    }
    __syncthreads();

    int r = tid >> 1, hf = tid & 1;
    const float* qrow = qb + base + (size_t)r * 32;
    float qv[32];
    #pragma unroll
    for (int d4 = 0; d4 < 8; ++d4)
        *(float4*)&qv[d4 * 4] = *(const float4*)&qrow[d4 * 4];

    const float* brow = biasf + ((size_t)head * 128 + r) * 128 + hf * 64;
    const float* mrow = mask  + ((size_t)wl * 128 + r) * 128 + hf * 64;

    float s[64];
    #pragma unroll
    for (int m = 0; m < 64; ++m) {
        int mg = (hf << 6) + m;
        float acc = 0.f;
        #pragma unroll
        for (int d4 = 0; d4 < 8; ++d4) {
            float4 k4 = *(const float4*)&Ks[mg][d4 * 4];
            acc += qv[d4 * 4 + 0] * k4.x + qv[d4 * 4 + 1] * k4.y
                 + qv[d4 * 4 + 2] * k4.z + qv[d4 * 4 + 3] * k4.w;
        }
        s[m] = acc + brow[m] + mrow[m];
    }
    float mx = -1e30f;
    #pragma unroll
    for (int m = 0; m < 64; ++m) mx = fmaxf(mx, s[m]);
    mx = fmaxf(mx, __shfl_xor(mx, 1));
    float sum = 0.f;
    #pragma unroll
    for (int m = 0; m < 64; ++m) { s[m] = __expf(s[m] - mx); sum += s[m]; }
    sum += __shfl_xor(sum, 1);
    float inv = 1.f / sum;

    float o[32] = {};
    #pragma unroll
    for (int m = 0; m < 64; ++m) {
        int mg = (hf << 6) + m;
        float p = s[m];
        #pragma unroll
        for (int d4 = 0; d4 < 8; ++d4) {
            float4 v4 = *(const float4*)&Vs[mg][d4 * 4];
            o[d4 * 4 + 0] += p * v4.x; o[d4 * 4 + 1] += p * v4.y;
            o[d4 * 4 + 2] += p * v4.z; o[d4 * 4 + 3] += p * v4.w;
        }
    }
    #pragma unroll
    for (int d = 0; d < 32; ++d) { o[d] += __shfl_xor(o[d], 1); o[d] *= inv; }

    float* orow = attn_out + ((size_t)(w_all * 128 + r)) * DIMC + head * 32 + hf * 16;
    #pragma unroll
    for (int d4 = 0; d4 < 4; ++d4) {
        int d = hf * 16 + d4 * 4;
        float4 v = make_float4(o[d], o[d + 1], o[d + 2], o[d + 3]);
        *(float4*)&orow[d4 * 4] = v;
    }
}

// ---------------- launch ----------------
extern "C" void kernel_launch(void* const* d_in, const int* in_sizes, int n_in,
                              void* d_out, int out_size, void* d_ws, size_t ws_size,
                              hipStream_t stream) {
    const float* x      = (const float*)d_in[0];
    const float* mask   = (const float*)d_in[1];
    const int*   rpi    = (const int*)d_in[2];
    const float* gamma1 = (const float*)d_in[3];
    const float* beta1  = (const float*)d_in[4];
    const float* w_qkv  = (const float*)d_in[5];
    const float* b_qkv  = (const float*)d_in[6];
    const float* rpb    = (const float*)d_in[7];
    const float* w_proj = (const float*)d_in[8];
    const float* b_proj = (const float*)d_in[9];
    const float* gamma2 = (const float*)d_in[10];
    const float* beta2  = (const float*)d_in[11];
    const float* w_fc1  = (const float*)d_in[12];
    const float* b_fc1  = (const float*)d_in[13];
    const float* w_fc2  = (const float*)d_in[14];
    const float* b_fc2  = (const float*)d_in[15];

    float* ws    = (float*)d_ws;
    float* xw    = ws + OFF_XW;    // xw -> attn_out -> y (LN2 out)
    float* qb    = ws + OFF_Q;
    float* kb    = ws + OFF_K;
    float* vb    = ws + OFF_V;
    float* hb    = ws + OFF_K;     // fc1 out overlays k,v (dead after attention)
    float* biasf = ws + OFF_BF;
    float* xres  = (float*)d_out;  // d_out doubles as xres (fully rewritten each call)

    k_bias<<<384, 256, 0, stream>>>(rpb, rpi, biasf);
    k_ln<true><<<16384, 256, 0, stream>>>(x, gamma1, beta1, xw);
    k_gemm<0><<<dim3(512, 9), 256, 0, stream>>>(xw, w_qkv, b_qkv, qb, nullptr, TOKS, 576, 192);
    k_attn<<<3072, 256, 0, stream>>>(qb, kb, vb, biasf, mask, xw);
    k_gemm<1><<<dim3(512, 3), 256, 0, stream>>>(xw, w_proj, b_proj, xres, x, TOKS, 192, 192);
    k_ln<false><<<16384, 256, 0, stream>>>(xres, gamma2, beta2, xw);
    k_gemm<2><<<dim3(512, 6), 256, 0, stream>>>(xw, w_fc1, b_fc1, hb, nullptr, TOKS, 384, 192);
    k_gemm<3><<<dim3(512, 3), 256, 0, stream>>>(hb, w_fc2, b_fc2, xres, xres, TOKS, 192, 384);
}

// Round 3
// 662.430 us; speedup vs baseline: 1.2394x; 1.2394x over previous
//
#include <hip/hip_runtime.h>
#include <hip/hip_bf16.h>
#include <math.h>

// ---- problem constants ----
#define TOKS   65536      // B*D*H*W = 2*8*64*64
#define DIMC   192
#define NWIN   512        // windows total (Bw)
#define NTOK   128        // tokens per window
#define NHEAD  6
#define HDIM   32
#define MLPH   384

typedef unsigned short u16;
typedef __attribute__((ext_vector_type(8))) short bf16x8;
typedef __attribute__((ext_vector_type(4))) float f32x4;

static __device__ __forceinline__ float gelu_exact(float v) {
    return 0.5f * v * (1.f + erff(v * 0.70710678118654752f));
}
static __device__ __forceinline__ u16 f2bf(float f) {
    __hip_bfloat16 h = __float2bfloat16(f);
    return *reinterpret_cast<u16*>(&h);
}

// workspace layout (float offsets)
#define OFF_XW   0u            // 65536*192 fp32 (xw / attn_out / y)
#define OFF_Q    12582912u     // q bf16 [wh][n][32]
#define OFF_K    25165824u     // k bf16 [wh][n][32]; fc1-out fp32 overlays OFF_K..OFF_BF after attn
#define OFF_V    37748736u     // vT bf16 [wh][d][128]
#define OFF_BF   50331648u     // bias_full fp32 [6][128][128] = 98304

// ---------------- rel-pos bias gather ----------------
__global__ __launch_bounds__(256) void k_bias(const float* __restrict__ rpb,
                                              const int* __restrict__ rpi,
                                              float* __restrict__ biasf) {
    int idx = blockIdx.x * 256 + threadIdx.x;   // 6*16384 = 98304 exact
    int h = idx >> 14;
    int nm = idx & 16383;
    biasf[idx] = rpb[rpi[nm] * 6 + h];
}

// ---------------- LayerNorm (opt. fused roll+window-partition gather) ----------------
template<bool PERMUTE>
__global__ __launch_bounds__(256) void k_ln(const float* __restrict__ x,
                                            const float* __restrict__ gamma,
                                            const float* __restrict__ beta,
                                            float* __restrict__ out) {
    int tid  = threadIdx.x;
    int lane = tid & 63, wv = tid >> 6;
    int tk = blockIdx.x * 4 + wv;
    size_t src;
    if (PERMUTE) {
        int w_all = tk >> 7, t = tk & 127;
        int b  = w_all >> 8, rem = w_all & 255;
        int di = rem >> 6, hi = (rem >> 3) & 7, wi = rem & 7;
        int qd = (di * 2 + (t >> 6) + 1) & 7;
        int qh = (hi * 8 + ((t >> 3) & 7) + 4) & 63;
        int qw = (wi * 8 + (t & 7) + 4) & 63;
        src = ((size_t)(((b * 8 + qd) * 64 + qh) * 64 + qw)) * DIMC;
    } else {
        src = (size_t)tk * DIMC;
    }
    float v0 = x[src + lane];
    float v1 = x[src + 64 + lane];
    float v2 = x[src + 128 + lane];
    float s  = v0 + v1 + v2;
    float sq = v0 * v0 + v1 * v1 + v2 * v2;
    #pragma unroll
    for (int off = 32; off; off >>= 1) {
        s  += __shfl_xor(s, off);
        sq += __shfl_xor(sq, off);
    }
    float mu   = s * (1.f / 192.f);
    float var  = sq * (1.f / 192.f) - mu * mu;
    float rstd = rsqrtf(var + 1e-5f);
    size_t o = (size_t)tk * DIMC;
    out[o + lane]       = (v0 - mu) * rstd * gamma[lane]       + beta[lane];
    out[o + 64 + lane]  = (v1 - mu) * rstd * gamma[64 + lane]  + beta[64 + lane];
    out[o + 128 + lane] = (v2 - mu) * rstd * gamma[128 + lane] + beta[128 + lane];
}

// ---------------- tiled SGEMM with fused epilogues ----------------
// MODE 0: QKV -> bf16 q/k [wh][t][32] (q scaled), bf16 vT [wh][d][128]
// MODE 1: proj -> roll-reverse scatter, += aux(x) -> out (=xres)
// MODE 2: fc1 -> gelu -> out[m*N+n]
// MODE 3: fc2 -> + aux -> out[m*192+n]
template<int MODE>
__global__ __launch_bounds__(256) void k_gemm(const float* __restrict__ A,
                                              const float* __restrict__ B,
                                              const float* __restrict__ bias,
                                              float* __restrict__ out,
                                              const float* __restrict__ aux,
                                              u16* __restrict__ q_o,
                                              u16* __restrict__ k_o,
                                              u16* __restrict__ v_o,
                                              int M, int N, int K) {
    __shared__ float As[32][132];
    __shared__ float Bs[32][68];
    int tid = threadIdx.x;
    int tx = tid & 15, ty = tid >> 4;
    int m0 = blockIdx.x * 128, n0 = blockIdx.y * 64;
    const float* Ab = A + (size_t)m0 * K;
    const float* Bb = B + (size_t)n0 * K;
    float acc[8][4] = {};
    for (int k0 = 0; k0 < K; k0 += 32) {
        #pragma unroll
        for (int j = 0; j < 4; ++j) {
            int id = j * 256 + tid;
            int r = id >> 3, c = (id & 7) << 2;
            float4 a = *(const float4*)&Ab[(size_t)r * K + k0 + c];
            As[c + 0][r] = a.x; As[c + 1][r] = a.y;
            As[c + 2][r] = a.z; As[c + 3][r] = a.w;
        }
        #pragma unroll
        for (int j = 0; j < 2; ++j) {
            int id = j * 256 + tid;
            int r = id >> 3, c = (id & 7) << 2;
            float4 b = *(const float4*)&Bb[(size_t)r * K + k0 + c];
            Bs[c + 0][r] = b.x; Bs[c + 1][r] = b.y;
            Bs[c + 2][r] = b.z; Bs[c + 3][r] = b.w;
        }
        __syncthreads();
        #pragma unroll
        for (int kk = 0; kk < 32; ++kk) {
            float4 b4 = *(float4*)&Bs[kk][tx * 4];
            float4 a0 = *(float4*)&As[kk][ty * 8];
            float4 a1 = *(float4*)&As[kk][ty * 8 + 4];
            float a[8] = {a0.x, a0.y, a0.z, a0.w, a1.x, a1.y, a1.z, a1.w};
            float b[4] = {b4.x, b4.y, b4.z, b4.w};
            #pragma unroll
            for (int i = 0; i < 8; ++i)
                #pragma unroll
                for (int j = 0; j < 4; ++j)
                    acc[i][j] += a[i] * b[j];
        }
        __syncthreads();
    }
    int mrow = m0 + ty * 8;
    int ncol = n0 + tx * 4;
    float bb0 = bias[ncol], bb1 = bias[ncol + 1], bb2 = bias[ncol + 2], bb3 = bias[ncol + 3];

    if (MODE == 0) {
        int sel = ncol / 192, rem = ncol - sel * 192;
        int head = rem >> 5, dd = rem & 31;
        float scale = (sel == 0) ? 0.17677669529663687f : 1.f;
        #pragma unroll
        for (int i = 0; i < 8; ++i) {
            int m = mrow + i, w = m >> 7, t = m & 127;
            size_t b9 = (size_t)(w * 6 + head) * 4096;
            u16 u0 = f2bf((acc[i][0] + bb0) * scale);
            u16 u1 = f2bf((acc[i][1] + bb1) * scale);
            u16 u2 = f2bf((acc[i][2] + bb2) * scale);
            u16 u3 = f2bf((acc[i][3] + bb3) * scale);
            if (sel < 2) {
                u16* dst = (sel == 0) ? q_o : k_o;
                ushort4 uv; uv.x = u0; uv.y = u1; uv.z = u2; uv.w = u3;
                *(ushort4*)&dst[b9 + (size_t)t * 32 + dd] = uv;
            } else {
                v_o[b9 + (size_t)(dd + 0) * 128 + t] = u0;
                v_o[b9 + (size_t)(dd + 1) * 128 + t] = u1;
                v_o[b9 + (size_t)(dd + 2) * 128 + t] = u2;
                v_o[b9 + (size_t)(dd + 3) * 128 + t] = u3;
            }
        }
    } else if (MODE == 1) {
        #pragma unroll
        for (int i = 0; i < 8; ++i) {
            int m = mrow + i, w_all = m >> 7, t = m & 127;
            int b  = w_all >> 8, rem = w_all & 255;
            int di = rem >> 6, hi = (rem >> 3) & 7, wi = rem & 7;
            int qd = (di * 2 + (t >> 6) + 1) & 7;
            int qh = (hi * 8 + ((t >> 3) & 7) + 4) & 63;
            int qw = (wi * 8 + (t & 7) + 4) & 63;
            size_t dtok = (size_t)(((b * 8 + qd) * 64 + qh) * 64 + qw);
            float4 xr = *(const float4*)&aux[dtok * DIMC + ncol];
            float4 v;
            v.x = acc[i][0] + bb0 + xr.x; v.y = acc[i][1] + bb1 + xr.y;
            v.z = acc[i][2] + bb2 + xr.z; v.w = acc[i][3] + bb3 + xr.w;
            *(float4*)&out[dtok * DIMC + ncol] = v;
        }
    } else if (MODE == 2) {
        #pragma unroll
        for (int i = 0; i < 8; ++i) {
            int m = mrow + i;
            float4 v;
            v.x = gelu_exact(acc[i][0] + bb0); v.y = gelu_exact(acc[i][1] + bb1);
            v.z = gelu_exact(acc[i][2] + bb2); v.w = gelu_exact(acc[i][3] + bb3);
            *(float4*)&out[(size_t)m * N + ncol] = v;
        }
    } else {
        #pragma unroll
        for (int i = 0; i < 8; ++i) {
            int m = mrow + i;
            float4 xr = *(const float4*)&aux[(size_t)m * DIMC + ncol];
            float4 v;
            v.x = acc[i][0] + bb0 + xr.x; v.y = acc[i][1] + bb1 + xr.y;
            v.z = acc[i][2] + bb2 + xr.z; v.w = acc[i][3] + bb3 + xr.w;
            *(float4*)&out[(size_t)m * DIMC + ncol] = v;
        }
    }
}

// ---------------- MFMA attention: one block (4 waves) per (window, head) ----------------
// wave wv owns rows [wv*32, wv*32+32). Q/K/vT bf16 fragments load straight from global.
// P goes through a per-wave XOR-swizzled LDS tile (D-layout -> A-layout transpose).
__global__ __launch_bounds__(256) void k_attn(const u16* __restrict__ qb,
                                              const u16* __restrict__ kb,
                                              const u16* __restrict__ vb,
                                              const float* __restrict__ biasf,
                                              const float* __restrict__ mask,
                                              float* __restrict__ attn_out) {
    __shared__ u16 Pl[4][32 * 128];     // 32 KB
    int wh = blockIdx.x;                 // == w_all*6 + head
    int w_all = wh / 6, head = wh - w_all * 6;
    int wl = w_all & 255;
    int tid = threadIdx.x;
    int wv = tid >> 6, l = tid & 63;
    int l15 = l & 15, g4 = l >> 4;
    size_t base = (size_t)wh * 4096;
    const u16* qg = qb + base;
    const u16* kg = kb + base;
    const u16* vg = vb + base;           // [d][m]
    int rowb = wv * 32;

    // Q A-fragments (rows rowb+rt*16+l15, k = g4*8..+8)
    bf16x8 qa[2];
    #pragma unroll
    for (int rt = 0; rt < 2; ++rt)
        qa[rt] = *(const bf16x8*)&qg[(size_t)(rowb + rt * 16 + l15) * 32 + g4 * 8];

    // QK^T: S[n][m], 2 row-tiles x 8 col-tiles
    f32x4 s[2][8] = {};
    #pragma unroll
    for (int ct = 0; ct < 8; ++ct) {
        bf16x8 kf = *(const bf16x8*)&kg[(size_t)(ct * 16 + l15) * 32 + g4 * 8];
        s[0][ct] = __builtin_amdgcn_mfma_f32_16x16x32_bf16(qa[0], kf, s[0][ct], 0, 0, 0);
        s[1][ct] = __builtin_amdgcn_mfma_f32_16x16x32_bf16(qa[1], kf, s[1][ct], 0, 0, 0);
    }

    // + bias + mask (fp32, L2-resident)
    const float* bh = biasf + (size_t)head * 16384;
    const float* mh = mask + (size_t)wl * 16384;
    #pragma unroll
    for (int rt = 0; rt < 2; ++rt)
        #pragma unroll
        for (int reg = 0; reg < 4; ++reg) {
            int n = rowb + rt * 16 + g4 * 4 + reg;
            #pragma unroll
            for (int ct = 0; ct < 8; ++ct) {
                int m = ct * 16 + l15;
                s[rt][ct][reg] += bh[n * 128 + m] + mh[n * 128 + m];
            }
        }

    // row softmax (row spread over 16 lanes sharing g4; 8 in-lane cols each)
    u16* Pw = Pl[wv];
    #pragma unroll
    for (int rt = 0; rt < 2; ++rt)
        #pragma unroll
        for (int reg = 0; reg < 4; ++reg) {
            float mx = -1e30f;
            #pragma unroll
            for (int ct = 0; ct < 8; ++ct) mx = fmaxf(mx, s[rt][ct][reg]);
            #pragma unroll
            for (int off = 1; off < 16; off <<= 1) mx = fmaxf(mx, __shfl_xor(mx, off));
            float sum = 0.f;
            #pragma unroll
            for (int ct = 0; ct < 8; ++ct) {
                float p = __expf(s[rt][ct][reg] - mx);
                s[rt][ct][reg] = p; sum += p;
            }
            #pragma unroll
            for (int off = 1; off < 16; off <<= 1) sum += __shfl_xor(sum, off);
            float inv = 1.f / sum;
            int n = rt * 16 + g4 * 4 + reg;         // local row
            int sw = ((n >> 2) & 3) << 4;
            #pragma unroll
            for (int ct = 0; ct < 8; ++ct) {
                int m = ct * 16 + l15;
                Pw[n * 128 + (m ^ sw)] = f2bf(s[rt][ct][reg] * inv);
            }
        }
    __syncthreads();

    // PV: O[n][d] = sum_m P[n][m] V[m][d]
    f32x4 o[2][2] = {};
    #pragma unroll
    for (int kt = 0; kt < 4; ++kt) {
        bf16x8 vf[2];
        #pragma unroll
        for (int dt = 0; dt < 2; ++dt)
            vf[dt] = *(const bf16x8*)&vg[(size_t)(dt * 16 + l15) * 128 + kt * 32 + g4 * 8];
        #pragma unroll
        for (int rt = 0; rt < 2; ++rt) {
            int n = rt * 16 + l15;
            int sw = ((n >> 2) & 3) << 4;
            int m8 = kt * 32 + g4 * 8;
            bf16x8 pa = *(const bf16x8*)&Pw[n * 128 + (m8 ^ sw)];
            #pragma unroll
            for (int dt = 0; dt < 2; ++dt)
                o[rt][dt] = __builtin_amdgcn_mfma_f32_16x16x32_bf16(pa, vf[dt], o[rt][dt], 0, 0, 0);
        }
    }

    // store O fp32 into attn_out[tok][head*32+d]
    #pragma unroll
    for (int rt = 0; rt < 2; ++rt)
        #pragma unroll
        for (int dt = 0; dt < 2; ++dt)
            #pragma unroll
            for (int reg = 0; reg < 4; ++reg) {
                int n = rowb + rt * 16 + g4 * 4 + reg;
                int d = dt * 16 + l15;
                attn_out[((size_t)(w_all * 128 + n)) * DIMC + head * 32 + d] = o[rt][dt][reg];
            }
}

// ---------------- launch ----------------
extern "C" void kernel_launch(void* const* d_in, const int* in_sizes, int n_in,
                              void* d_out, int out_size, void* d_ws, size_t ws_size,
                              hipStream_t stream) {
    const float* x      = (const float*)d_in[0];
    const float* mask   = (const float*)d_in[1];
    const int*   rpi    = (const int*)d_in[2];
    const float* gamma1 = (const float*)d_in[3];
    const float* beta1  = (const float*)d_in[4];
    const float* w_qkv  = (const float*)d_in[5];
    const float* b_qkv  = (const float*)d_in[6];
    const float* rpb    = (const float*)d_in[7];
    const float* w_proj = (const float*)d_in[8];
    const float* b_proj = (const float*)d_in[9];
    const float* gamma2 = (const float*)d_in[10];
    const float* beta2  = (const float*)d_in[11];
    const float* w_fc1  = (const float*)d_in[12];
    const float* b_fc1  = (const float*)d_in[13];
    const float* w_fc2  = (const float*)d_in[14];
    const float* b_fc2  = (const float*)d_in[15];

    float* ws    = (float*)d_ws;
    float* xw    = ws + OFF_XW;           // fp32 xw -> attn_out -> y
    u16*   qbu   = (u16*)(ws + OFF_Q);    // bf16 q
    u16*   kbu   = (u16*)(ws + OFF_K);    // bf16 k
    u16*   vbu   = (u16*)(ws + OFF_V);    // bf16 vT
    float* hb    = ws + OFF_K;            // fc1 out fp32 overlays k/v (dead after attn)
    float* biasf = ws + OFF_BF;
    float* xres  = (float*)d_out;

    k_bias<<<384, 256, 0, stream>>>(rpb, rpi, biasf);
    k_ln<true><<<16384, 256, 0, stream>>>(x, gamma1, beta1, xw);
    k_gemm<0><<<dim3(512, 9), 256, 0, stream>>>(xw, w_qkv, b_qkv, nullptr, nullptr,
                                                qbu, kbu, vbu, TOKS, 576, 192);
    k_attn<<<3072, 256, 0, stream>>>(qbu, kbu, vbu, biasf, mask, xw);
    k_gemm<1><<<dim3(512, 3), 256, 0, stream>>>(xw, w_proj, b_proj, xres, x,
                                                nullptr, nullptr, nullptr, TOKS, 192, 192);
    k_ln<false><<<16384, 256, 0, stream>>>(xres, gamma2, beta2, xw);
    k_gemm<2><<<dim3(512, 6), 256, 0, stream>>>(xw, w_fc1, b_fc1, hb, nullptr,
                                                nullptr, nullptr, nullptr, TOKS, 384, 192);
    k_gemm<3><<<dim3(512, 3), 256, 0, stream>>>(hb, w_fc2, b_fc2, xres, xres,
                                                nullptr, nullptr, nullptr, TOKS, 192, 384);
}

// Round 4
// 241.286 us; speedup vs baseline: 3.4027x; 2.7454x over previous
//
#include <hip/hip_runtime.h>
#include <hip/hip_bf16.h>
#include <math.h>

// ---- problem constants ----
#define TOKS   65536      // B*D*H*W
#define DIMC   192
#define NTOK   128
#define MLPH   384
#define QSCALE 0.17677669529663687f

typedef unsigned short u16;
typedef __attribute__((ext_vector_type(8))) short bf16x8;
typedef __attribute__((ext_vector_type(4))) float f32x4;

static __device__ __forceinline__ float gelu_exact(float v) {
    return 0.5f * v * (1.f + erff(v * 0.70710678118654752f));
}
static __device__ __forceinline__ u16 f2bf(float f) {
    __hip_bfloat16 h = __float2bfloat16(f);
    return *reinterpret_cast<u16*>(&h);
}
static __device__ __forceinline__ void gl_lds16(const u16* g, u16* l) {
    __builtin_amdgcn_global_load_lds(
        (const __attribute__((address_space(1))) void*)g,
        (__attribute__((address_space(3))) void*)l, 16, 0, 0);
}

// workspace layout (float offsets). bf16 buffers occupy elems/2 floats.
#define OFF_XW   0u          // xw bf16 [65536][192] -> attn_out bf16 overlay
#define OFF_Q    6291456u    // q bf16 [wh][t][32];  h bf16 [65536][384] overlays Q..V
#define OFF_K    12582912u   // k bf16
#define OFF_V    18874368u   // vT bf16 [wh][d][128]; y (LN2 out) bf16 overlay
#define OFF_BF   25165824u   // bias_full fp32 [6][128][128]
#define OFF_WB   25264128u   // bf16 weights: qkv 110592 | proj @110592 | fc1 @147456 | fc2 @221184

// ---------------- weight fp32 -> bf16 (294912 elements total) ----------------
__global__ __launch_bounds__(256) void k_cvt(const float* __restrict__ a,   // qkv 110592
                                             const float* __restrict__ b,   // proj 36864
                                             const float* __restrict__ c,   // fc1 73728
                                             const float* __restrict__ d,   // fc2 73728
                                             u16* __restrict__ o) {
    int i = blockIdx.x * 256 + threadIdx.x;   // 1152*256 = 294912 exact
    float v;
    if (i < 110592) v = a[i];
    else if (i < 147456) v = b[i - 110592];
    else if (i < 221184) v = c[i - 147456];
    else v = d[i - 221184];
    o[i] = f2bf(v);
}

// ---------------- rel-pos bias gather ----------------
__global__ __launch_bounds__(256) void k_bias(const float* __restrict__ rpb,
                                              const int* __restrict__ rpi,
                                              float* __restrict__ biasf) {
    int idx = blockIdx.x * 256 + threadIdx.x;   // 98304 exact
    int h = idx >> 14;
    int nm = idx & 16383;
    biasf[idx] = rpb[rpi[nm] * 6 + h];
}

// ---------------- LayerNorm -> bf16 (opt. fused roll+window gather) ----------------
template<bool PERMUTE>
__global__ __launch_bounds__(256) void k_ln(const float* __restrict__ x,
                                            const float* __restrict__ gamma,
                                            const float* __restrict__ beta,
                                            u16* __restrict__ out) {
    int tid  = threadIdx.x;
    int lane = tid & 63, wv = tid >> 6;
    int tk = blockIdx.x * 4 + wv;
    size_t src;
    if (PERMUTE) {
        int w_all = tk >> 7, t = tk & 127;
        int b  = w_all >> 8, rem = w_all & 255;
        int di = rem >> 6, hi = (rem >> 3) & 7, wi = rem & 7;
        int qd = (di * 2 + (t >> 6) + 1) & 7;
        int qh = (hi * 8 + ((t >> 3) & 7) + 4) & 63;
        int qw = (wi * 8 + (t & 7) + 4) & 63;
        src = ((size_t)(((b * 8 + qd) * 64 + qh) * 64 + qw)) * DIMC;
    } else {
        src = (size_t)tk * DIMC;
    }
    float v0 = x[src + lane];
    float v1 = x[src + 64 + lane];
    float v2 = x[src + 128 + lane];
    float s  = v0 + v1 + v2;
    float sq = v0 * v0 + v1 * v1 + v2 * v2;
    #pragma unroll
    for (int off = 32; off; off >>= 1) {
        s  += __shfl_xor(s, off);
        sq += __shfl_xor(sq, off);
    }
    float mu   = s * (1.f / 192.f);
    float var  = sq * (1.f / 192.f) - mu * mu;
    float rstd = rsqrtf(var + 1e-5f);
    size_t o = (size_t)tk * DIMC;
    out[o + lane]       = f2bf((v0 - mu) * rstd * gamma[lane]       + beta[lane]);
    out[o + 64 + lane]  = f2bf((v1 - mu) * rstd * gamma[64 + lane]  + beta[64 + lane]);
    out[o + 128 + lane] = f2bf((v2 - mu) * rstd * gamma[128 + lane] + beta[128 + lane]);
}

// ---------------- bf16 MFMA GEMM: C[m,n] = A[m,:].W[n,:] + bias[n] ----------------
// BM=128 BN=64 BK=64, 4 waves (2x2), A via global_load_lds (pre-swizzled src),
// W read direct from global (L1/L2-resident). fp32 epilogues per MODE.
// MODE 0: QKV -> q/k bf16 [wh][t][32] (q scaled), vT bf16 [wh][d][128]
// MODE 1: proj -> roll-reverse scatter += aux(x fp32) -> fp32 out (xres)
// MODE 2: fc1 -> gelu -> bf16 out [m][384]
// MODE 3: fc2 -> += aux fp32 -> fp32 out [m][192]
template<int MODE, int KD>
__global__ __launch_bounds__(256) void k_mgemm(const u16* __restrict__ A,
                                               const u16* __restrict__ W,
                                               const float* __restrict__ bias,
                                               void* __restrict__ outp,
                                               const float* __restrict__ aux,
                                               u16* __restrict__ q_o,
                                               u16* __restrict__ k_o,
                                               u16* __restrict__ v_o) {
    __shared__ u16 As[2][128 * 64];          // 2 x 16 KB
    const int tid = threadIdx.x;
    const int wv = tid >> 6, l = tid & 63;
    const int l15 = l & 15, g4 = l >> 4;
    const int wm = wv >> 1, wn = wv & 1;
    const size_t m0 = (size_t)blockIdx.x * 128;
    const int n0 = blockIdx.y * 64;
    const int srow = l >> 3, scol = l & 7;

    f32x4 acc[4][2] = {};

    auto STAGE = [&](int b, int t) {
        const u16* Ab = A + m0 * KD + t * 64;
        #pragma unroll
        for (int j = 0; j < 4; ++j) {
            int row = (wv * 4 + j) * 8 + srow;
            int sc  = scol ^ (row & 7);
            gl_lds16(Ab + (size_t)row * KD + sc * 8, &As[b][(wv * 4 + j) * 512]);
        }
    };
    auto COMPUTE = [&](int b, int t) {
        #pragma unroll
        for (int kk = 0; kk < 2; ++kk) {
            bf16x8 bfr[2];
            #pragma unroll
            for (int nt = 0; nt < 2; ++nt)
                bfr[nt] = *(const bf16x8*)&W[(size_t)(n0 + wn * 32 + nt * 16 + l15) * KD
                                             + t * 64 + kk * 32 + g4 * 8];
            #pragma unroll
            for (int mt = 0; mt < 4; ++mt) {
                int row  = wm * 64 + mt * 16 + l15;
                int slot = (kk * 4 + g4) ^ (row & 7);
                bf16x8 afr = *(const bf16x8*)&As[b][row * 64 + slot * 8];
                #pragma unroll
                for (int nt = 0; nt < 2; ++nt)
                    acc[mt][nt] = __builtin_amdgcn_mfma_f32_16x16x32_bf16(afr, bfr[nt],
                                                                          acc[mt][nt], 0, 0, 0);
            }
        }
    };

    constexpr int NT = KD / 64;
    STAGE(0, 0);
    __syncthreads();
    for (int t = 0; t < NT; ++t) {
        if (t + 1 < NT) STAGE((t + 1) & 1, t + 1);
        COMPUTE(t & 1, t);
        __syncthreads();
    }

    // epilogue: global row m = m0 + wm*64 + mt*16 + g4*4 + reg ; col n = n0 + wn*32 + nt*16 + l15
    #pragma unroll
    for (int mt = 0; mt < 4; ++mt) {
        #pragma unroll
        for (int nt = 0; nt < 2; ++nt) {
            int n  = n0 + wn * 32 + nt * 16 + l15;
            float bb = bias[n];
            int t0 = wm * 64 + mt * 16 + g4 * 4;        // local token/row base
            if (MODE == 0) {
                int sel = (n >= 384) ? 2 : (n >= 192 ? 1 : 0);
                int rem = n - sel * 192;
                int head = rem >> 5, dd = rem & 31;
                int w = (int)(m0 >> 7);
                size_t b9 = (size_t)(w * 6 + head) * 4096;
                if (sel < 2) {
                    u16* dst = sel ? k_o : q_o;
                    float scl = sel ? 1.f : QSCALE;
                    #pragma unroll
                    for (int reg = 0; reg < 4; ++reg)
                        dst[b9 + (size_t)(t0 + reg) * 32 + dd] = f2bf((acc[mt][nt][reg] + bb) * scl);
                } else {
                    ushort4 uv;
                    uv.x = f2bf(acc[mt][nt][0] + bb); uv.y = f2bf(acc[mt][nt][1] + bb);
                    uv.z = f2bf(acc[mt][nt][2] + bb); uv.w = f2bf(acc[mt][nt][3] + bb);
                    *(ushort4*)&v_o[b9 + (size_t)dd * 128 + t0] = uv;
                }
            } else if (MODE == 1) {
                float* out = (float*)outp;
                #pragma unroll
                for (int reg = 0; reg < 4; ++reg) {
                    int m = (int)m0 + wm * 64 + mt * 16 + g4 * 4 + reg;
                    int w_all = m >> 7, tt = m & 127;
                    int b  = w_all >> 8, rem = w_all & 255;
                    int di = rem >> 6, hi = (rem >> 3) & 7, wi = rem & 7;
                    int qd = (di * 2 + (tt >> 6) + 1) & 7;
                    int qh = (hi * 8 + ((tt >> 3) & 7) + 4) & 63;
                    int qw = (wi * 8 + (tt & 7) + 4) & 63;
                    size_t dtok = (size_t)(((b * 8 + qd) * 64 + qh) * 64 + qw);
                    out[dtok * DIMC + n] = acc[mt][nt][reg] + bb + aux[dtok * DIMC + n];
                }
            } else if (MODE == 2) {
                u16* out = (u16*)outp;
                #pragma unroll
                for (int reg = 0; reg < 4; ++reg) {
                    size_t m = m0 + t0 + reg;
                    out[m * MLPH + n] = f2bf(gelu_exact(acc[mt][nt][reg] + bb));
                }
            } else {
                float* out = (float*)outp;
                #pragma unroll
                for (int reg = 0; reg < 4; ++reg) {
                    size_t m = m0 + t0 + reg;
                    out[m * DIMC + n] = acc[mt][nt][reg] + bb + aux[m * DIMC + n];
                }
            }
        }
    }
}

// ---------------- MFMA attention: one block (4 waves) per (window, head) ----------------
__global__ __launch_bounds__(256) void k_attn(const u16* __restrict__ qb,
                                              const u16* __restrict__ kb,
                                              const u16* __restrict__ vb,
                                              const float* __restrict__ biasf,
                                              const float* __restrict__ mask,
                                              u16* __restrict__ attn_out) {
    __shared__ u16 Pl[4][32 * 128];     // 32 KB
    int wh = blockIdx.x;
    int w_all = wh / 6, head = wh - w_all * 6;
    int wl = w_all & 255;
    int tid = threadIdx.x;
    int wv = tid >> 6, l = tid & 63;
    int l15 = l & 15, g4 = l >> 4;
    size_t base = (size_t)wh * 4096;
    const u16* qg = qb + base;
    const u16* kg = kb + base;
    const u16* vg = vb + base;           // [d][m]
    int rowb = wv * 32;

    bf16x8 qa[2];
    #pragma unroll
    for (int rt = 0; rt < 2; ++rt)
        qa[rt] = *(const bf16x8*)&qg[(size_t)(rowb + rt * 16 + l15) * 32 + g4 * 8];

    f32x4 s[2][8] = {};
    #pragma unroll
    for (int ct = 0; ct < 8; ++ct) {
        bf16x8 kf = *(const bf16x8*)&kg[(size_t)(ct * 16 + l15) * 32 + g4 * 8];
        s[0][ct] = __builtin_amdgcn_mfma_f32_16x16x32_bf16(qa[0], kf, s[0][ct], 0, 0, 0);
        s[1][ct] = __builtin_amdgcn_mfma_f32_16x16x32_bf16(qa[1], kf, s[1][ct], 0, 0, 0);
    }

    const float* bh = biasf + (size_t)head * 16384;
    const float* mh = mask + (size_t)wl * 16384;
    #pragma unroll
    for (int rt = 0; rt < 2; ++rt)
        #pragma unroll
        for (int reg = 0; reg < 4; ++reg) {
            int n = rowb + rt * 16 + g4 * 4 + reg;
            #pragma unroll
            for (int ct = 0; ct < 8; ++ct) {
                int m = ct * 16 + l15;
                s[rt][ct][reg] += bh[n * 128 + m] + mh[n * 128 + m];
            }
        }

    u16* Pw = Pl[wv];
    #pragma unroll
    for (int rt = 0; rt < 2; ++rt)
        #pragma unroll
        for (int reg = 0; reg < 4; ++reg) {
            float mx = -1e30f;
            #pragma unroll
            for (int ct = 0; ct < 8; ++ct) mx = fmaxf(mx, s[rt][ct][reg]);
            #pragma unroll
            for (int off = 1; off < 16; off <<= 1) mx = fmaxf(mx, __shfl_xor(mx, off));
            float sum = 0.f;
            #pragma unroll
            for (int ct = 0; ct < 8; ++ct) {
                float p = __expf(s[rt][ct][reg] - mx);
                s[rt][ct][reg] = p; sum += p;
            }
            #pragma unroll
            for (int off = 1; off < 16; off <<= 1) sum += __shfl_xor(sum, off);
            float inv = 1.f / sum;
            int nloc = rt * 16 + g4 * 4 + reg;
            int sw = ((nloc >> 2) & 3) << 4;
            #pragma unroll
            for (int ct = 0; ct < 8; ++ct) {
                int m = ct * 16 + l15;
                Pw[nloc * 128 + (m ^ sw)] = f2bf(s[rt][ct][reg] * inv);
            }
        }
    __syncthreads();

    f32x4 o[2][2] = {};
    #pragma unroll
    for (int kt = 0; kt < 4; ++kt) {
        bf16x8 vf[2];
        #pragma unroll
        for (int dt = 0; dt < 2; ++dt)
            vf[dt] = *(const bf16x8*)&vg[(size_t)(dt * 16 + l15) * 128 + kt * 32 + g4 * 8];
        #pragma unroll
        for (int rt = 0; rt < 2; ++rt) {
            int nloc = rt * 16 + l15;
            int sw = ((nloc >> 2) & 3) << 4;
            int m8 = kt * 32 + g4 * 8;
            bf16x8 pa = *(const bf16x8*)&Pw[nloc * 128 + (m8 ^ sw)];
            #pragma unroll
            for (int dt = 0; dt < 2; ++dt)
                o[rt][dt] = __builtin_amdgcn_mfma_f32_16x16x32_bf16(pa, vf[dt], o[rt][dt], 0, 0, 0);
        }
    }

    #pragma unroll
    for (int rt = 0; rt < 2; ++rt)
        #pragma unroll
        for (int dt = 0; dt < 2; ++dt)
            #pragma unroll
            for (int reg = 0; reg < 4; ++reg) {
                int n = rowb + rt * 16 + g4 * 4 + reg;
                int d = dt * 16 + l15;
                attn_out[((size_t)(w_all * 128 + n)) * DIMC + head * 32 + d] = f2bf(o[rt][dt][reg]);
            }
}

// ---------------- launch ----------------
extern "C" void kernel_launch(void* const* d_in, const int* in_sizes, int n_in,
                              void* d_out, int out_size, void* d_ws, size_t ws_size,
                              hipStream_t stream) {
    const float* x      = (const float*)d_in[0];
    const float* mask   = (const float*)d_in[1];
    const int*   rpi    = (const int*)d_in[2];
    const float* gamma1 = (const float*)d_in[3];
    const float* beta1  = (const float*)d_in[4];
    const float* w_qkv  = (const float*)d_in[5];
    const float* b_qkv  = (const float*)d_in[6];
    const float* rpb    = (const float*)d_in[7];
    const float* w_proj = (const float*)d_in[8];
    const float* b_proj = (const float*)d_in[9];
    const float* gamma2 = (const float*)d_in[10];
    const float* beta2  = (const float*)d_in[11];
    const float* w_fc1  = (const float*)d_in[12];
    const float* b_fc1  = (const float*)d_in[13];
    const float* w_fc2  = (const float*)d_in[14];
    const float* b_fc2  = (const float*)d_in[15];

    float* ws    = (float*)d_ws;
    u16*   xwu   = (u16*)(ws + OFF_XW);   // LN1 out; attn_out overlays after QKV
    u16*   qbu   = (u16*)(ws + OFF_Q);
    u16*   kbu   = (u16*)(ws + OFF_K);
    u16*   vbu   = (u16*)(ws + OFF_V);
    u16*   hbu   = (u16*)(ws + OFF_Q);    // fc1 out overlays q+k (dead after attn)
    u16*   ybu   = (u16*)(ws + OFF_V);    // LN2 out overlays vT (dead after attn)
    float* biasf = ws + OFF_BF;
    u16*   wb    = (u16*)(ws + OFF_WB);
    float* xres  = (float*)d_out;

    const u16* wqkv_b = wb;
    const u16* wproj_b = wb + 110592;
    const u16* wfc1_b = wb + 147456;
    const u16* wfc2_b = wb + 221184;

    k_cvt<<<1152, 256, 0, stream>>>(w_qkv, w_proj, w_fc1, w_fc2, wb);
    k_bias<<<384, 256, 0, stream>>>(rpb, rpi, biasf);
    k_ln<true><<<16384, 256, 0, stream>>>(x, gamma1, beta1, xwu);
    k_mgemm<0, 192><<<dim3(512, 9), 256, 0, stream>>>(xwu, wqkv_b, b_qkv, nullptr, nullptr,
                                                      qbu, kbu, vbu);
    k_attn<<<3072, 256, 0, stream>>>(qbu, kbu, vbu, biasf, mask, xwu);
    k_mgemm<1, 192><<<dim3(512, 3), 256, 0, stream>>>(xwu, wproj_b, b_proj, xres, x,
                                                      nullptr, nullptr, nullptr);
    k_ln<false><<<16384, 256, 0, stream>>>(xres, gamma2, beta2, ybu);
    k_mgemm<2, 192><<<dim3(512, 6), 256, 0, stream>>>(ybu, wfc1_b, b_fc1, hbu, nullptr,
                                                      nullptr, nullptr, nullptr);
    k_mgemm<3, 384><<<dim3(512, 3), 256, 0, stream>>>(hbu, wfc2_b, b_fc2, xres, xres,
                                                      nullptr, nullptr, nullptr);
}

// Round 5
// 222.163 us; speedup vs baseline: 3.6956x; 1.0861x over previous
//
#include <hip/hip_runtime.h>
#include <hip/hip_bf16.h>
#include <math.h>

// ---- problem constants ----
#define TOKS   65536      // B*D*H*W
#define DIMC   192
#define NTOK   128
#define MLPH   384
#define QSCALE 0.17677669529663687f

typedef unsigned short u16;
typedef unsigned int   u32;
typedef __attribute__((ext_vector_type(8))) short bf16x8;
typedef __attribute__((ext_vector_type(4))) float f32x4;

static __device__ __forceinline__ float gelu_exact(float v) {
    return 0.5f * v * (1.f + erff(v * 0.70710678118654752f));
}
static __device__ __forceinline__ u16 f2bf(float f) {
    __hip_bfloat16 h = __float2bfloat16(f);
    return *reinterpret_cast<u16*>(&h);
}
static __device__ __forceinline__ float bf2f(u16 b) {
    u32 u = ((u32)b) << 16;
    float f;
    __builtin_memcpy(&f, &u, 4);
    return f;
}
static __device__ __forceinline__ void gl_lds16(const u16* g, u16* l) {
    __builtin_amdgcn_global_load_lds(
        (const __attribute__((address_space(1))) void*)g,
        (__attribute__((address_space(3))) void*)l, 16, 0, 0);
}

// workspace layout (float offsets). bf16 buffers occupy elems/2 floats.
#define OFF_XW   0u          // xw bf16 [65536][192] -> attn_out bf16 overlay
#define OFF_Q    6291456u    // q bf16 [wh][t][32];  h bf16 [65536][384] overlays Q..V
#define OFF_K    12582912u   // k bf16
#define OFF_V    18874368u   // vT bf16 [wh][d][128]; y (LN2 out) bf16 overlay
#define OFF_BF   25165824u   // biasw bf16 [6][128][128] (fragment-tiled) = 98304 u16
#define OFF_WB   25264128u   // bf16 weights: qkv | proj @110592 | fc1 @147456 | fc2 @221184

// ---------------- weight fp32 -> bf16 ----------------
__global__ __launch_bounds__(256) void k_cvt(const float* __restrict__ a,
                                             const float* __restrict__ b,
                                             const float* __restrict__ c,
                                             const float* __restrict__ d,
                                             u16* __restrict__ o) {
    int i = blockIdx.x * 256 + threadIdx.x;   // 1152*256 = 294912 exact
    float v;
    if (i < 110592) v = a[i];
    else if (i < 147456) v = b[i - 110592];
    else if (i < 221184) v = c[i - 147456];
    else v = d[i - 221184];
    o[i] = f2bf(v);
}

// ---------------- rel-pos bias gather -> bf16, MFMA-fragment-tiled ----------------
// biasw[h][n][slot], slot = (m&15)*8 + (m>>4): thread (l15,g4) reads its 8 ct values
// for row n as ONE contiguous bf16x8 at &biasw[(h*128+n)*128 + l15*8].
__global__ __launch_bounds__(256) void k_bias(const float* __restrict__ rpb,
                                              const int* __restrict__ rpi,
                                              u16* __restrict__ biasw) {
    int idx = blockIdx.x * 256 + threadIdx.x;   // 6*128*128 = 98304 exact
    int h = idx >> 14;
    int n = (idx >> 7) & 127;
    int slot = idx & 127;
    int m = ((slot & 7) << 4) + (slot >> 3);
    biasw[idx] = f2bf(rpb[rpi[n * 128 + m] * 6 + h]);
}

// ---------------- LayerNorm -> bf16 (opt. fused roll+window gather) ----------------
template<bool PERMUTE>
__global__ __launch_bounds__(256) void k_ln(const float* __restrict__ x,
                                            const float* __restrict__ gamma,
                                            const float* __restrict__ beta,
                                            u16* __restrict__ out) {
    int tid  = threadIdx.x;
    int lane = tid & 63, wv = tid >> 6;
    int tk = blockIdx.x * 4 + wv;
    size_t src;
    if (PERMUTE) {
        int w_all = tk >> 7, t = tk & 127;
        int b  = w_all >> 8, rem = w_all & 255;
        int di = rem >> 6, hi = (rem >> 3) & 7, wi = rem & 7;
        int qd = (di * 2 + (t >> 6) + 1) & 7;
        int qh = (hi * 8 + ((t >> 3) & 7) + 4) & 63;
        int qw = (wi * 8 + (t & 7) + 4) & 63;
        src = ((size_t)(((b * 8 + qd) * 64 + qh) * 64 + qw)) * DIMC;
    } else {
        src = (size_t)tk * DIMC;
    }
    float v0 = x[src + lane];
    float v1 = x[src + 64 + lane];
    float v2 = x[src + 128 + lane];
    float s  = v0 + v1 + v2;
    float sq = v0 * v0 + v1 * v1 + v2 * v2;
    #pragma unroll
    for (int off = 32; off; off >>= 1) {
        s  += __shfl_xor(s, off);
        sq += __shfl_xor(sq, off);
    }
    float mu   = s * (1.f / 192.f);
    float var  = sq * (1.f / 192.f) - mu * mu;
    float rstd = rsqrtf(var + 1e-5f);
    size_t o = (size_t)tk * DIMC;
    out[o + lane]       = f2bf((v0 - mu) * rstd * gamma[lane]       + beta[lane]);
    out[o + 64 + lane]  = f2bf((v1 - mu) * rstd * gamma[64 + lane]  + beta[64 + lane]);
    out[o + 128 + lane] = f2bf((v2 - mu) * rstd * gamma[128 + lane] + beta[128 + lane]);
}

// ---------------- bf16 MFMA GEMM (BM=128 BN=64 BK=64, 4 waves) ----------------
template<int MODE, int KD>
__global__ __launch_bounds__(256) void k_mgemm(const u16* __restrict__ A,
                                               const u16* __restrict__ W,
                                               const float* __restrict__ bias,
                                               void* __restrict__ outp,
                                               const float* __restrict__ aux,
                                               u16* __restrict__ q_o,
                                               u16* __restrict__ k_o,
                                               u16* __restrict__ v_o) {
    __shared__ u16 As[2][128 * 64];          // 2 x 16 KB
    const int tid = threadIdx.x;
    const int wv = tid >> 6, l = tid & 63;
    const int l15 = l & 15, g4 = l >> 4;
    const int wm = wv >> 1, wn = wv & 1;
    const size_t m0 = (size_t)blockIdx.x * 128;
    const int n0 = blockIdx.y * 64;
    const int srow = l >> 3, scol = l & 7;

    f32x4 acc[4][2] = {};

    auto STAGE = [&](int b, int t) {
        const u16* Ab = A + m0 * KD + t * 64;
        #pragma unroll
        for (int j = 0; j < 4; ++j) {
            int row = (wv * 4 + j) * 8 + srow;
            int sc  = scol ^ (row & 7);
            gl_lds16(Ab + (size_t)row * KD + sc * 8, &As[b][(wv * 4 + j) * 512]);
        }
    };
    auto COMPUTE = [&](int b, int t) {
        #pragma unroll
        for (int kk = 0; kk < 2; ++kk) {
            bf16x8 bfr[2];
            #pragma unroll
            for (int nt = 0; nt < 2; ++nt)
                bfr[nt] = *(const bf16x8*)&W[(size_t)(n0 + wn * 32 + nt * 16 + l15) * KD
                                             + t * 64 + kk * 32 + g4 * 8];
            #pragma unroll
            for (int mt = 0; mt < 4; ++mt) {
                int row  = wm * 64 + mt * 16 + l15;
                int slot = (kk * 4 + g4) ^ (row & 7);
                bf16x8 afr = *(const bf16x8*)&As[b][row * 64 + slot * 8];
                #pragma unroll
                for (int nt = 0; nt < 2; ++nt)
                    acc[mt][nt] = __builtin_amdgcn_mfma_f32_16x16x32_bf16(afr, bfr[nt],
                                                                          acc[mt][nt], 0, 0, 0);
            }
        }
    };

    constexpr int NT = KD / 64;
    STAGE(0, 0);
    __syncthreads();
    for (int t = 0; t < NT; ++t) {
        if (t + 1 < NT) STAGE((t + 1) & 1, t + 1);
        COMPUTE(t & 1, t);
        __syncthreads();
    }

    #pragma unroll
    for (int mt = 0; mt < 4; ++mt) {
        #pragma unroll
        for (int nt = 0; nt < 2; ++nt) {
            int n  = n0 + wn * 32 + nt * 16 + l15;
            float bb = bias[n];
            int t0 = wm * 64 + mt * 16 + g4 * 4;
            if (MODE == 0) {
                int sel = (n >= 384) ? 2 : (n >= 192 ? 1 : 0);
                int rem = n - sel * 192;
                int head = rem >> 5, dd = rem & 31;
                int w = (int)(m0 >> 7);
                size_t b9 = (size_t)(w * 6 + head) * 4096;
                if (sel < 2) {
                    u16* dst = sel ? k_o : q_o;
                    float scl = sel ? 1.f : QSCALE;
                    #pragma unroll
                    for (int reg = 0; reg < 4; ++reg)
                        dst[b9 + (size_t)(t0 + reg) * 32 + dd] = f2bf((acc[mt][nt][reg] + bb) * scl);
                } else {
                    ushort4 uv;
                    uv.x = f2bf(acc[mt][nt][0] + bb); uv.y = f2bf(acc[mt][nt][1] + bb);
                    uv.z = f2bf(acc[mt][nt][2] + bb); uv.w = f2bf(acc[mt][nt][3] + bb);
                    *(ushort4*)&v_o[b9 + (size_t)dd * 128 + t0] = uv;
                }
            } else if (MODE == 1) {
                float* out = (float*)outp;
                #pragma unroll
                for (int reg = 0; reg < 4; ++reg) {
                    int m = (int)m0 + wm * 64 + mt * 16 + g4 * 4 + reg;
                    int w_all = m >> 7, tt = m & 127;
                    int b  = w_all >> 8, rem = w_all & 255;
                    int di = rem >> 6, hi = (rem >> 3) & 7, wi = rem & 7;
                    int qd = (di * 2 + (tt >> 6) + 1) & 7;
                    int qh = (hi * 8 + ((tt >> 3) & 7) + 4) & 63;
                    int qw = (wi * 8 + (tt & 7) + 4) & 63;
                    size_t dtok = (size_t)(((b * 8 + qd) * 64 + qh) * 64 + qw);
                    out[dtok * DIMC + n] = acc[mt][nt][reg] + bb + aux[dtok * DIMC + n];
                }
            } else if (MODE == 2) {
                u16* out = (u16*)outp;
                #pragma unroll
                for (int reg = 0; reg < 4; ++reg) {
                    size_t m = m0 + t0 + reg;
                    out[m * MLPH + n] = f2bf(gelu_exact(acc[mt][nt][reg] + bb));
                }
            } else {
                float* out = (float*)outp;
                #pragma unroll
                for (int reg = 0; reg < 4; ++reg) {
                    size_t m = m0 + t0 + reg;
                    out[m * DIMC + n] = acc[mt][nt][reg] + bb + aux[m * DIMC + n];
                }
            }
        }
    }
}

// ---------------- MFMA attention ----------------
// bias: one bf16x8 load per (rt,reg); mask: closed-form region compare (no loads).
__global__ __launch_bounds__(256) void k_attn(const u16* __restrict__ qb,
                                              const u16* __restrict__ kb,
                                              const u16* __restrict__ vb,
                                              const u16* __restrict__ biasw,
                                              u16* __restrict__ attn_out) {
    __shared__ u16 Pl[4][32 * 128];     // 32 KB
    int wh = blockIdx.x;
    int w_all = wh / 6, head = wh - w_all * 6;
    int wl = w_all & 255;
    int tid = threadIdx.x;
    int wv = tid >> 6, l = tid & 63;
    int l15 = l & 15, g4 = l >> 4;
    size_t base = (size_t)wh * 4096;
    const u16* qg = qb + base;
    const u16* kg = kb + base;
    const u16* vg = vb + base;           // [d][m]
    int rowb = wv * 32;

    bf16x8 qa[2];
    #pragma unroll
    for (int rt = 0; rt < 2; ++rt)
        qa[rt] = *(const bf16x8*)&qg[(size_t)(rowb + rt * 16 + l15) * 32 + g4 * 8];

    f32x4 s[2][8] = {};
    #pragma unroll
    for (int ct = 0; ct < 8; ++ct) {
        bf16x8 kf = *(const bf16x8*)&kg[(size_t)(ct * 16 + l15) * 32 + g4 * 8];
        s[0][ct] = __builtin_amdgcn_mfma_f32_16x16x32_bf16(qa[0], kf, s[0][ct], 0, 0, 0);
        s[1][ct] = __builtin_amdgcn_mfma_f32_16x16x32_bf16(qa[1], kf, s[1][ct], 0, 0, 0);
    }

    // region code of token t in window wl (canvas coords; Swin shift mask)
    int di = wl >> 6, hi = (wl >> 3) & 7, wi = wl & 7;
    auto rcode = [&](int t) {
        int d = di * 2 + (t >> 6);
        int h = hi * 8 + ((t >> 3) & 7);
        int w = wi * 8 + (t & 7);
        int rd = (d < 6) ? 0 : (d < 7 ? 1 : 2);
        int rh = (h < 56) ? 0 : (h < 60 ? 1 : 2);
        int rw = (w < 56) ? 0 : (w < 60 ? 1 : 2);
        return rd * 9 + rh * 3 + rw;
    };
    int rm[8];
    #pragma unroll
    for (int ct = 0; ct < 8; ++ct) rm[ct] = rcode(ct * 16 + l15);

    const u16* bh = biasw + (size_t)head * 16384;
    #pragma unroll
    for (int rt = 0; rt < 2; ++rt)
        #pragma unroll
        for (int reg = 0; reg < 4; ++reg) {
            int n = rowb + rt * 16 + g4 * 4 + reg;
            int rn = rcode(n);
            bf16x8 bv = *(const bf16x8*)&bh[(size_t)n * 128 + l15 * 8];
            #pragma unroll
            for (int ct = 0; ct < 8; ++ct) {
                float mval = (rn == rm[ct]) ? 0.f : -100.f;
                s[rt][ct][reg] += bf2f((u16)bv[ct]) + mval;
            }
        }

    u16* Pw = Pl[wv];
    #pragma unroll
    for (int rt = 0; rt < 2; ++rt)
        #pragma unroll
        for (int reg = 0; reg < 4; ++reg) {
            float mx = -1e30f;
            #pragma unroll
            for (int ct = 0; ct < 8; ++ct) mx = fmaxf(mx, s[rt][ct][reg]);
            #pragma unroll
            for (int off = 1; off < 16; off <<= 1) mx = fmaxf(mx, __shfl_xor(mx, off));
            float sum = 0.f;
            #pragma unroll
            for (int ct = 0; ct < 8; ++ct) {
                float p = __expf(s[rt][ct][reg] - mx);
                s[rt][ct][reg] = p; sum += p;
            }
            #pragma unroll
            for (int off = 1; off < 16; off <<= 1) sum += __shfl_xor(sum, off);
            float inv = 1.f / sum;
            int nloc = rt * 16 + g4 * 4 + reg;
            int sw = ((nloc >> 2) & 3) << 4;
            #pragma unroll
            for (int ct = 0; ct < 8; ++ct) {
                int m = ct * 16 + l15;
                Pw[nloc * 128 + (m ^ sw)] = f2bf(s[rt][ct][reg] * inv);
            }
        }
    __syncthreads();

    f32x4 o[2][2] = {};
    #pragma unroll
    for (int kt = 0; kt < 4; ++kt) {
        bf16x8 vf[2];
        #pragma unroll
        for (int dt = 0; dt < 2; ++dt)
            vf[dt] = *(const bf16x8*)&vg[(size_t)(dt * 16 + l15) * 128 + kt * 32 + g4 * 8];
        #pragma unroll
        for (int rt = 0; rt < 2; ++rt) {
            int nloc = rt * 16 + l15;
            int sw = ((nloc >> 2) & 3) << 4;
            int m8 = kt * 32 + g4 * 8;
            bf16x8 pa = *(const bf16x8*)&Pw[nloc * 128 + (m8 ^ sw)];
            #pragma unroll
            for (int dt = 0; dt < 2; ++dt)
                o[rt][dt] = __builtin_amdgcn_mfma_f32_16x16x32_bf16(pa, vf[dt], o[rt][dt], 0, 0, 0);
        }
    }

    #pragma unroll
    for (int rt = 0; rt < 2; ++rt)
        #pragma unroll
        for (int dt = 0; dt < 2; ++dt)
            #pragma unroll
            for (int reg = 0; reg < 4; ++reg) {
                int n = rowb + rt * 16 + g4 * 4 + reg;
                int d = dt * 16 + l15;
                attn_out[((size_t)(w_all * 128 + n)) * DIMC + head * 32 + d] = f2bf(o[rt][dt][reg]);
            }
}

// ---------------- launch ----------------
extern "C" void kernel_launch(void* const* d_in, const int* in_sizes, int n_in,
                              void* d_out, int out_size, void* d_ws, size_t ws_size,
                              hipStream_t stream) {
    const float* x      = (const float*)d_in[0];
    const int*   rpi    = (const int*)d_in[2];
    const float* gamma1 = (const float*)d_in[3];
    const float* beta1  = (const float*)d_in[4];
    const float* w_qkv  = (const float*)d_in[5];
    const float* b_qkv  = (const float*)d_in[6];
    const float* rpb    = (const float*)d_in[7];
    const float* w_proj = (const float*)d_in[8];
    const float* b_proj = (const float*)d_in[9];
    const float* gamma2 = (const float*)d_in[10];
    const float* beta2  = (const float*)d_in[11];
    const float* w_fc1  = (const float*)d_in[12];
    const float* b_fc1  = (const float*)d_in[13];
    const float* w_fc2  = (const float*)d_in[14];
    const float* b_fc2  = (const float*)d_in[15];

    float* ws    = (float*)d_ws;
    u16*   xwu   = (u16*)(ws + OFF_XW);   // LN1 out; attn_out overlays after QKV
    u16*   qbu   = (u16*)(ws + OFF_Q);
    u16*   kbu   = (u16*)(ws + OFF_K);
    u16*   vbu   = (u16*)(ws + OFF_V);
    u16*   hbu   = (u16*)(ws + OFF_Q);    // fc1 out overlays q+k (dead after attn)
    u16*   ybu   = (u16*)(ws + OFF_V);    // LN2 out overlays vT (dead after attn)
    u16*   biasw = (u16*)(ws + OFF_BF);
    u16*   wb    = (u16*)(ws + OFF_WB);
    float* xres  = (float*)d_out;

    const u16* wqkv_b = wb;
    const u16* wproj_b = wb + 110592;
    const u16* wfc1_b = wb + 147456;
    const u16* wfc2_b = wb + 221184;

    k_cvt<<<1152, 256, 0, stream>>>(w_qkv, w_proj, w_fc1, w_fc2, wb);
    k_bias<<<384, 256, 0, stream>>>(rpb, rpi, biasw);
    k_ln<true><<<16384, 256, 0, stream>>>(x, gamma1, beta1, xwu);
    k_mgemm<0, 192><<<dim3(512, 9), 256, 0, stream>>>(xwu, wqkv_b, b_qkv, nullptr, nullptr,
                                                      qbu, kbu, vbu);
    k_attn<<<3072, 256, 0, stream>>>(qbu, kbu, vbu, biasw, xwu);
    k_mgemm<1, 192><<<dim3(512, 3), 256, 0, stream>>>(xwu, wproj_b, b_proj, xres, x,
                                                      nullptr, nullptr, nullptr);
    k_ln<false><<<16384, 256, 0, stream>>>(xres, gamma2, beta2, ybu);
    k_mgemm<2, 192><<<dim3(512, 6), 256, 0, stream>>>(ybu, wfc1_b, b_fc1, hbu, nullptr,
                                                      nullptr, nullptr, nullptr);
    k_mgemm<3, 384><<<dim3(512, 3), 256, 0, stream>>>(hbu, wfc2_b, b_fc2, xres, xres,
                                                      nullptr, nullptr, nullptr);
}